// Round 3
// baseline (1626.775 us; speedup 1.0000x reference)
//
#include <hip/hip_runtime.h>

// HSI_RWKV fused block kernel — VALU diagnostic/baseline version.
// out = block(x) + T(block(T(x))) == 2 * block_per_token(x)  (block is per-token).
// Thread (w,l) of a 256-thread block owns token (blockIdx*64 + l), channels
// [32w, 32w+32). Every GEMV output is computed directly by its owning thread:
// no MFMA, no C-layout scatter — isolates R2's failure to the MFMA path.
// Activations round-trip LDS as bf16 (same pack helpers as the MFMA version);
// weights fp32; residual t fp32 in registers.

#define HW   16384
#define CDIM 128
#define LDA  132   // ushort stride per 64x128 bf16 LDS row (264 B, 8B-aligned)

__device__ __forceinline__ float bf2f(ushort h) {
    union { uint u; float f; } v; v.u = ((uint)h) << 16; return v.f;
}
__device__ __forceinline__ ushort f2bf(float f) {
    union { float f; uint u; } v; v.f = f;
    uint u = v.u + 0x7fffu + ((v.u >> 16) & 1u);   // RNE
    return (ushort)(u >> 16);
}
__device__ __forceinline__ float sigm(float x) {
    return 1.f / (1.f + __expf(-x));
}

// acc[i] = sum_k bf(Arow[k]) * W0[i*ldw + k],  k in [0,128), i in [0,32)
__device__ __forceinline__ void gemv32(const ushort* __restrict__ Arow,
                                       const float* __restrict__ W0,
                                       int ldw, float acc[32]) {
#pragma unroll
    for (int i = 0; i < 32; ++i) acc[i] = 0.f;
#pragma unroll 1
    for (int k = 0; k < 128; k += 8) {
        float s[8];
#pragma unroll
        for (int j = 0; j < 8; ++j) s[j] = bf2f(Arow[k + j]);
#pragma unroll
        for (int i = 0; i < 32; ++i) {
            const float* wp = W0 + i * ldw + k;
            float4 wa = *(const float4*)wp;
            float4 wb = *(const float4*)(wp + 4);
            acc[i] += s[0]*wa.x + s[1]*wa.y + s[2]*wa.z + s[3]*wa.w
                    + s[4]*wb.x + s[5]*wb.y + s[6]*wb.z + s[7]*wb.w;
        }
    }
}

__device__ __forceinline__ void stats(const float* t, float* red, int w, int l,
                                      float& mu, float& rs) {
    float s1 = 0.f, s2 = 0.f;
#pragma unroll
    for (int i = 0; i < 32; ++i) { s1 += t[i]; s2 += t[i]*t[i]; }
    __syncthreads();                       // guard red reuse
    red[w*64 + l] = s1; red[256 + w*64 + l] = s2;
    __syncthreads();
    float S1 = red[l] + red[64+l] + red[128+l] + red[192+l];
    float S2 = red[256+l] + red[320+l] + red[384+l] + red[448+l];
    mu = S1 * (1.f/128.f);
    rs = rsqrtf(S2 * (1.f/128.f) - mu*mu + 1e-5f);
}

__global__ __launch_bounds__(256) void rwkv_valu(
    const float* __restrict__ X,
    const float* __restrict__ G0, const float* __restrict__ B0,
    const float* __restrict__ G1, const float* __restrict__ B1,
    const float* __restrict__ G2, const float* __restrict__ B2,
    const float* __restrict__ Wout, const float* __restrict__ Wwht,
    const float* __restrict__ Wkey, const float* __restrict__ Wrec,
    const float* __restrict__ Wval,
    float* __restrict__ Y)
{
    __shared__ __align__(16) ushort Ab[64 * LDA];    // a1 / y2 / k-chunk (bf16)
    __shared__ __align__(16) ushort WHT[64 * LDA];   // wht (bf16)
    __shared__ float red[512];

    const int tid = threadIdx.x;
    const int w = tid >> 6, l = tid & 63;
    const int g0tok = blockIdx.x * 64;
    const int b  = g0tok >> 14;
    const int s0 = g0tok & (HW - 1);
    const int base = (b * CDIM) * HW + s0 + l;      // + ch*HW per channel

    // ---- load: token l, channels 32w..32w+31 ----
    float t[32];
#pragma unroll
    for (int i = 0; i < 32; ++i)
        t[i] = X[base + (32*w + i) * HW];

    float mu, rs;
    // ---- LN0 ----
    stats(t, red, w, l, mu, rs);
#pragma unroll
    for (int i = 0; i < 32; ++i) {
        int ch = 32*w + i;
        t[i] = (t[i] - mu) * rs * G0[ch] + B0[ch];
    }
    // ---- LN1, a1 = silu(y1) -> Ab ----
    stats(t, red, w, l, mu, rs);
#pragma unroll
    for (int j = 0; j < 16; ++j) {
        int ch = 32*w + 2*j;
        float y0 = (t[2*j]   - mu) * rs * G1[ch]   + B1[ch];
        float y1 = (t[2*j+1] - mu) * rs * G1[ch+1] + B1[ch+1];
        float a0 = y0 * sigm(y0);
        float a1 = y1 * sigm(y1);
        *(uint*)&Ab[l*LDA + ch] = (uint)f2bf(a0) | ((uint)f2bf(a1) << 16);
    }
    __syncthreads();                                 // a1 visible

    // ---- att = a1 @ W_out^T ; t += att ----
    float acc[32];
    gemv32(&Ab[l*LDA], Wout + (32*w)*128, 128, acc);
#pragma unroll
    for (int i = 0; i < 32; ++i) t[i] += acc[i];
    __syncthreads();                                 // att reads of Ab done

    // ---- LN2 -> y2 -> Ab ----
    stats(t, red, w, l, mu, rs);
#pragma unroll
    for (int j = 0; j < 16; ++j) {
        int ch = 32*w + 2*j;
        float y0 = (t[2*j]   - mu) * rs * G2[ch]   + B2[ch];
        float y1 = (t[2*j+1] - mu) * rs * G2[ch+1] + B2[ch+1];
        *(uint*)&Ab[l*LDA + ch] = (uint)f2bf(y0) | ((uint)f2bf(y1) << 16);
    }
    __syncthreads();                                 // y2 visible

    // ---- wht = y2 @ W_whiten^T -> WHT ----
    gemv32(&Ab[l*LDA], Wwht + (32*w)*128, 128, acc);
#pragma unroll
    for (int j = 0; j < 16; ++j)
        *(uint*)&WHT[l*LDA + 32*w + 2*j] =
            (uint)f2bf(acc[2*j]) | ((uint)f2bf(acc[2*j+1]) << 16);
    __syncthreads();                                 // wht visible; y2 reads done

    // ---- kv = sum_chunks relu(wht@W_key^T)^2 @ W_value^T ----
    float kv[32];
#pragma unroll
    for (int i = 0; i < 32; ++i) kv[i] = 0.f;
    for (int chunk = 0; chunk < 4; ++chunk) {
        gemv32(&WHT[l*LDA], Wkey + (chunk*128 + 32*w)*128, 128, acc);
        __syncthreads();                             // prev Ab readers done
#pragma unroll
        for (int j = 0; j < 16; ++j) {
            float v0 = fmaxf(acc[2*j],   0.f);
            float v1 = fmaxf(acc[2*j+1], 0.f);
            *(uint*)&Ab[l*LDA + 32*w + 2*j] =
                (uint)f2bf(v0*v0) | ((uint)f2bf(v1*v1) << 16);
        }
        __syncthreads();                             // k-chunk visible
        gemv32(&Ab[l*LDA], Wval + (32*w)*512 + chunk*128, 512, acc);
#pragma unroll
        for (int i = 0; i < 32; ++i) kv[i] += acc[i];
    }

    // ---- r = sigmoid(wht @ W_recep^T); t += r*kv; out = 2t ----
    gemv32(&WHT[l*LDA], Wrec + (32*w)*128, 128, acc);
#pragma unroll
    for (int i = 0; i < 32; ++i) {
        float t2 = t[i] + sigm(acc[i]) * kv[i];
        Y[base + (32*w + i) * HW] = 2.f * t2;
    }
}

extern "C" void kernel_launch(void* const* d_in, const int* in_sizes, int n_in,
                              void* d_out, int out_size, void* d_ws, size_t ws_size,
                              hipStream_t stream) {
    (void)in_sizes; (void)n_in; (void)out_size; (void)d_ws; (void)ws_size;
    rwkv_valu<<<dim3(65536 / 64), dim3(256), 0, stream>>>(
        (const float*)d_in[0],
        (const float*)d_in[1], (const float*)d_in[2],
        (const float*)d_in[3], (const float*)d_in[4],
        (const float*)d_in[5], (const float*)d_in[6],
        (const float*)d_in[7], (const float*)d_in[8],
        (const float*)d_in[9], (const float*)d_in[10],
        (const float*)d_in[11],
        (float*)d_out);
}

// Round 5
// 322.447 us; speedup vs baseline: 5.0451x; 5.0451x over previous
//
#include <hip/hip_runtime.h>

// HSI_RWKV fused block kernel, MI355X (gfx950), MFMA version (R5).
// out = block(x) + T(block(T(x))) == 2 * block_per_token(x)  (block is per-token).
// Wave-local: each wave owns 16 tokens x 128 channels; all GEMMs are
// 16x128 @ 128xN via v_mfma_f32_16x16x32_bf16, nt=8 column tiles.
// Layout convention (AMD matrix-instruction-calculator, m89/m91/m120):
//   A: m=lane&15, k=quad*8+j    B: n=lane&15, k=quad*8+j
//   D: M=quad*4+reg, N=lane&15
// R2/R4 bug (fixed here): fp32 LDS views overran the per-wave ushort slices
// (16x132 ushorts = 4224 B, fp32 view needed 8448 B) -> cross-wave clobber.
// Fix: att and r*kv round-trip LDS as bf16 in the correctly-sized buffers.

#define HW    16384
#define CDIM  128
#define LDA   132     // ushorts per LDS activation row (264 B, 8B-aligned)
#define NW    4       // waves per block
#define TPW   16      // tokens per wave

// ws offsets in ushort elements
#define OFF_OUT 0
#define OFF_WHT 16384
#define OFF_KEY 32768
#define OFF_REC 98304
#define OFF_VAL 114688
#define WS_ELEMS 180224   // *2 bytes = 360448

typedef __attribute__((ext_vector_type(8))) short short8;  // 8 bf16 bit patterns
typedef __attribute__((ext_vector_type(4))) float f32x4;

__device__ __forceinline__ float bf2f(ushort h) {
    union { uint u; float f; } v; v.u = ((uint)h) << 16; return v.f;
}
__device__ __forceinline__ ushort f2bf(float f) {
    union { float f; uint u; } v; v.f = f;
    uint u = v.u + 0x7fffu + ((v.u >> 16) & 1u);   // RNE
    return (ushort)(u >> 16);
}
__device__ __forceinline__ float sigm(float x) {
    return 1.f / (1.f + __expf(-x));
}

__global__ void cvt_weights(const float* __restrict__ src,
                            ushort* __restrict__ dst, int n) {
    int i = blockIdx.x * 256 + threadIdx.x;
    if (i < n) dst[i] = f2bf(src[i]);
}

template<bool PRE>
__device__ __forceinline__ short8 ldB(const ushort* __restrict__ Wb,
                                      const float* __restrict__ Wf, int idx) {
    if (PRE) return *(const short8*)(Wb + idx);    // 16B aligned
    union { ushort u[8]; short8 s; } r;
    const float* p = Wf + idx;
    float4 f0 = *(const float4*)p;
    float4 f1 = *(const float4*)(p + 4);
    r.u[0]=f2bf(f0.x); r.u[1]=f2bf(f0.y); r.u[2]=f2bf(f0.z); r.u[3]=f2bf(f0.w);
    r.u[4]=f2bf(f1.x); r.u[5]=f2bf(f1.y); r.u[6]=f2bf(f1.z); r.u[7]=f2bf(f1.w);
    return r.s;
}

// acc[nt] += A(16 tokens x K=128, LDS bf16) @ W[row0+nt*16+..][kbase+..]^T
template<bool PRE>
__device__ __forceinline__ void gemm16x128(
    const ushort* A, const ushort* __restrict__ Wb, const float* __restrict__ Wf,
    int ldw, int row0, int kbase, int q, int c, f32x4 acc[8])
{
#pragma unroll
    for (int kk = 0; kk < 4; ++kk) {
        short8 a;
        {
            union { uint2 x[2]; short8 s; } r;
            const ushort* p = A + c * LDA + kk * 32 + q * 8;
            r.x[0] = *(const uint2*)p;
            r.x[1] = *(const uint2*)(p + 4);
            a = r.s;
        }
#pragma unroll
        for (int nt = 0; nt < 8; ++nt) {
            int idx = (row0 + nt * 16 + c) * ldw + kbase + kk * 32 + q * 8;
            short8 b = ldB<PRE>(Wb, Wf, idx);
            acc[nt] = __builtin_amdgcn_mfma_f32_16x16x32_bf16(a, b, acc[nt], 0, 0, 0);
        }
    }
}

__device__ __forceinline__ void zero8(f32x4 a[8]) {
#pragma unroll
    for (int nt = 0; nt < 8; ++nt) a[nt] = (f32x4){0.f, 0.f, 0.f, 0.f};
}

// per-token LN stats: token = lane&15, partials across the 4 quads
__device__ __forceinline__ void ln_stats(const float* t, float& mu, float& rs) {
    float s1 = 0.f, s2 = 0.f;
#pragma unroll
    for (int i = 0; i < 32; ++i) { s1 += t[i]; s2 += t[i] * t[i]; }
    s1 += __shfl_xor(s1, 16); s2 += __shfl_xor(s2, 16);
    s1 += __shfl_xor(s1, 32); s2 += __shfl_xor(s2, 32);
    mu = s1 * (1.f / 128.f);
    rs = rsqrtf(s2 * (1.f / 128.f) - mu * mu + 1e-5f);
}

template<bool PRE>
__global__ __launch_bounds__(256) void rwkv_mfma(
    const float* __restrict__ X,
    const float* __restrict__ G0, const float* __restrict__ B0,
    const float* __restrict__ G1, const float* __restrict__ B1,
    const float* __restrict__ G2, const float* __restrict__ B2,
    const float* __restrict__ WoutF, const float* __restrict__ WwhtF,
    const float* __restrict__ WkeyF, const float* __restrict__ WrecF,
    const float* __restrict__ WvalF,
    const ushort* __restrict__ Wb,
    float* __restrict__ Y)
{
    __shared__ __align__(16) ushort actS[NW * TPW * LDA];
    __shared__ __align__(16) ushort whtS[NW * TPW * LDA];

    const int tid = threadIdx.x;
    const int w = tid >> 6, l = tid & 63;
    const int q = l >> 4, c = l & 15;
    ushort* act = actS + w * (TPW * LDA);   // a1 / y2 / k-chunk / prod (bf16)
    ushort* wht = whtS + w * (TPW * LDA);   // att temp, then wht (bf16)

    const int s64 = blockIdx.x * 64;           // 64 tokens per block
    const int b   = s64 >> 14;
    const int s0  = s64 & (HW - 1);
    const long gbase = (long)(b * CDIM) * HW + s0 + 16 * w + c;

    // ---- residual: token 16w+c, channels 32q..32q+31 ----
    float t[32];
#pragma unroll
    for (int i = 0; i < 32; ++i) t[i] = X[gbase + (long)(32 * q + i) * HW];

    float mu, rs;
    // ---- LN0 ----
    ln_stats(t, mu, rs);
#pragma unroll
    for (int i = 0; i < 32; ++i) {
        int ch = 32 * q + i;
        t[i] = (t[i] - mu) * rs * G0[ch] + B0[ch];
    }
    // ---- LN1 + silu -> act (bf16) ----
    ln_stats(t, mu, rs);
#pragma unroll
    for (int j = 0; j < 16; ++j) {
        int ch = 32 * q + 2 * j;
        float y0 = (t[2*j]   - mu) * rs * G1[ch]   + B1[ch];
        float y1 = (t[2*j+1] - mu) * rs * G1[ch+1] + B1[ch+1];
        y0 *= sigm(y0); y1 *= sigm(y1);
        *(uint*)&act[c * LDA + ch] = (uint)f2bf(y0) | ((uint)f2bf(y1) << 16);
    }
    __syncthreads();

    // ---- att = a1 @ W_out^T -> bf16 scatter into wht buffer (att temp) ----
    f32x4 acc[8];
    zero8(acc);
    gemm16x128<PRE>(act, Wb + OFF_OUT, WoutF, 128, 0, 0, q, c, acc);
#pragma unroll
    for (int nt = 0; nt < 8; ++nt)
#pragma unroll
        for (int r = 0; r < 4; ++r)
            wht[(q * 4 + r) * LDA + nt * 16 + c] = f2bf(acc[nt][r]);
    __syncthreads();
#pragma unroll
    for (int i = 0; i < 32; ++i)
        t[i] += bf2f(wht[c * LDA + 32 * q + i]);          // t1 = t + att

    // ---- LN2 -> act (bf16, overwrite a1) ----
    ln_stats(t, mu, rs);
    __syncthreads();                     // att temp fully consumed
#pragma unroll
    for (int j = 0; j < 16; ++j) {
        int ch = 32 * q + 2 * j;
        float y0 = (t[2*j]   - mu) * rs * G2[ch]   + B2[ch];
        float y1 = (t[2*j+1] - mu) * rs * G2[ch+1] + B2[ch+1];
        *(uint*)&act[c * LDA + ch] = (uint)f2bf(y0) | ((uint)f2bf(y1) << 16);
    }
    __syncthreads();

    // ---- wht = y2 @ W_whiten^T -> wht buffer (bf16, overwrites att temp) ----
    zero8(acc);
    gemm16x128<PRE>(act, Wb + OFF_WHT, WwhtF, 128, 0, 0, q, c, acc);
#pragma unroll
    for (int nt = 0; nt < 8; ++nt)
#pragma unroll
        for (int r = 0; r < 4; ++r)
            wht[(q * 4 + r) * LDA + nt * 16 + c] = f2bf(acc[nt][r]);
    __syncthreads();

    // ---- kv = sum_chunks relu(wht @ W_key^T)^2 @ W_value^T ----
    f32x4 akv[8];
    zero8(akv);
    for (int chunk = 0; chunk < 4; ++chunk) {
        zero8(acc);
        gemm16x128<PRE>(wht, Wb + OFF_KEY, WkeyF, 128, chunk * 128, 0, q, c, acc);
        __syncthreads();                 // prior act readers done
#pragma unroll
        for (int nt = 0; nt < 8; ++nt)
#pragma unroll
            for (int r = 0; r < 4; ++r) {
                float v = fmaxf(acc[nt][r], 0.f);
                act[(q * 4 + r) * LDA + nt * 16 + c] = f2bf(v * v);
            }
        __syncthreads();                 // k-chunk visible
        gemm16x128<PRE>(act, Wb + OFF_VAL, WvalF, 512, 0, chunk * 128, q, c, akv);
    }

    // ---- r = sigmoid(wht @ W_recep^T); prod = r*kv -> act (bf16) ----
    zero8(acc);
    gemm16x128<PRE>(wht, Wb + OFF_REC, WrecF, 128, 0, 0, q, c, acc);
    __syncthreads();                     // act readers (val GEMM) done
#pragma unroll
    for (int nt = 0; nt < 8; ++nt)
#pragma unroll
        for (int r = 0; r < 4; ++r)
            act[(q * 4 + r) * LDA + nt * 16 + c] = f2bf(sigm(acc[nt][r]) * akv[nt][r]);
    __syncthreads();

    // ---- out = 2 * (t1 + r*kv) ----
#pragma unroll
    for (int i = 0; i < 32; ++i) {
        float t2 = t[i] + bf2f(act[c * LDA + 32 * q + i]);
        Y[gbase + (long)(32 * q + i) * HW] = 2.f * t2;
    }
}

extern "C" void kernel_launch(void* const* d_in, const int* in_sizes, int n_in,
                              void* d_out, int out_size, void* d_ws, size_t ws_size,
                              hipStream_t stream) {
    (void)in_sizes; (void)n_in; (void)out_size;
    const float* X  = (const float*)d_in[0];
    const float* G0 = (const float*)d_in[1];  const float* B0 = (const float*)d_in[2];
    const float* G1 = (const float*)d_in[3];  const float* B1 = (const float*)d_in[4];
    const float* G2 = (const float*)d_in[5];  const float* B2 = (const float*)d_in[6];
    const float* Wout = (const float*)d_in[7];
    const float* Wwht = (const float*)d_in[8];
    const float* Wkey = (const float*)d_in[9];
    const float* Wrec = (const float*)d_in[10];
    const float* Wval = (const float*)d_in[11];
    float* Y = (float*)d_out;

    const bool pre = ws_size >= (size_t)WS_ELEMS * 2;
    if (pre) {
        ushort* ws = (ushort*)d_ws;
        cvt_weights<<<64,  256, 0, stream>>>(Wout, ws + OFF_OUT, 16384);
        cvt_weights<<<64,  256, 0, stream>>>(Wwht, ws + OFF_WHT, 16384);
        cvt_weights<<<256, 256, 0, stream>>>(Wkey, ws + OFF_KEY, 65536);
        cvt_weights<<<64,  256, 0, stream>>>(Wrec, ws + OFF_REC, 16384);
        cvt_weights<<<256, 256, 0, stream>>>(Wval, ws + OFF_VAL, 65536);
        rwkv_mfma<true><<<1024, 256, 0, stream>>>(
            X, G0, B0, G1, B1, G2, B2,
            Wout, Wwht, Wkey, Wrec, Wval, ws, Y);
    } else {
        rwkv_mfma<false><<<1024, 256, 0, stream>>>(
            X, G0, B0, G1, B1, G2, B2,
            Wout, Wwht, Wkey, Wrec, Wval, nullptr, Y);
    }
}

// Round 8
// 205.456 us; speedup vs baseline: 7.9179x; 1.5694x over previous
//
#include <hip/hip_runtime.h>

// HSI_RWKV fused block kernel, MI355X (gfx950), R8.
// out = block(x) + T(block(T(x))) == 2 * block_per_token(x)  (block is per-token).
// Structure: R5's PROVEN wave-local design (passed full harness incl. graph
// replay): wave owns 16 tokens x 128 channels; act/wht LDS slices wave-local.
// R6/R7's cross-wave activation sharing raced under replay -> abandoned.
// R8 change vs R5: B-fragments come from an LDS-staged weight tile (128x136
// padded bf16), staged per GEMM phase by all 256 threads with batched 16B
// loads. R5's bottleneck was one L2 round-trip PER MFMA (32 serial global
// B-loads/GEMM ~= 12.8K cy/phase); staging batches that into one round-trip
// per tile, and ds_read_b128 B-access pipelines via lgkmcnt.
// MFMA layouts (m89/m91): A m=lane&15,k=q*8+j; B n=lane&15,k=q*8+j;
// D row(token)=q*4+reg, col(out-ch)=lane&15. Frags: short8 bit patterns.

#define HW    16384
#define CDIM  128
#define LDA   132     // act row stride (ushorts); 264 B, 8B-aligned
#define LDW   136     // weight tile row stride (ushorts); 272 B -> ~2-way banks
#define TPW   16      // tokens per wave
#define NW    4

#define OFF_OUT 0
#define OFF_WHT 16384
#define OFF_KEY 32768
#define OFF_REC 98304
#define OFF_VAL 114688
#define WS_ELEMS 180224   // *2 bytes

typedef __attribute__((ext_vector_type(8))) short short8;  // 8 bf16 bit patterns
typedef __attribute__((ext_vector_type(4))) float f32x4;

__device__ __forceinline__ float bf2f(ushort h) {
    union { uint u; float f; } v; v.u = ((uint)h) << 16; return v.f;
}
__device__ __forceinline__ ushort f2bf(float f) {
    union { float f; uint u; } v; v.f = f;
    uint u = v.u + 0x7fffu + ((v.u >> 16) & 1u);   // RNE
    return (ushort)(u >> 16);
}
__device__ __forceinline__ float sigm(float x) {
    return 1.f / (1.f + __expf(-x));
}

// one-launch weight conversion: 180224 elements, grid 704 x 256 (proven R7 first-launch)
__global__ void cvt_all(const float* __restrict__ Wout, const float* __restrict__ Wwht,
                        const float* __restrict__ Wkey, const float* __restrict__ Wrec,
                        const float* __restrict__ Wval, ushort* __restrict__ ws) {
    int i = blockIdx.x * 256 + threadIdx.x;
    float v;
    if      (i < 32768)  v = (i < 16384) ? Wout[i] : Wwht[i - 16384];
    else if (i < 98304)  v = Wkey[i - 32768];
    else if (i < 114688) v = Wrec[i - 98304];
    else                 v = Wval[i - 114688];
    ws[i] = f2bf(v);
}

// Stage a 128x128 bf16 tile W[row0..row0+128)[k0..k0+128) into Wl (LDW-padded).
// 256 threads x 16B x 8 iters = 32 KB; batched independent loads.
template<bool PRE>
__device__ __forceinline__ void stageW(ushort* Wl,
                                       const ushort* __restrict__ wsrc,
                                       const float* __restrict__ fsrc,
                                       int src_ld, int row0, int k0, int tid) {
    const int rr = tid >> 4, cc = (tid & 15) * 8;
#pragma unroll
    for (int j = 0; j < 8; ++j) {
        const int r  = j * 16 + rr;
        const int si = (row0 + r) * src_ld + k0 + cc;
        if (PRE) {
            *(short8*)&Wl[r * LDW + cc] = *(const short8*)&wsrc[si];
        } else {
            const float* p = fsrc + si;
            float4 f0 = *(const float4*)p;
            float4 f1 = *(const float4*)(p + 4);
            union { ushort u[8]; short8 s; } t;
            t.u[0]=f2bf(f0.x); t.u[1]=f2bf(f0.y); t.u[2]=f2bf(f0.z); t.u[3]=f2bf(f0.w);
            t.u[4]=f2bf(f1.x); t.u[5]=f2bf(f1.y); t.u[6]=f2bf(f1.z); t.u[7]=f2bf(f1.w);
            *(short8*)&Wl[r * LDW + cc] = t.s;
        }
    }
}

__device__ __forceinline__ short8 ldA8(const ushort* p) {   // 8B-aligned LDS
    union { uint2 x[2]; short8 s; } r;
    r.x[0] = *(const uint2*)p;
    r.x[1] = *(const uint2*)(p + 4);
    return r.s;
}

// acc[nt] += A(16 tok x K=128, wave-local LDS) @ Wl(128x128 LDS tile)^T
__device__ __forceinline__ void gemm16(const ushort* A, const ushort* Wl,
                                       int q, int c, f32x4 acc[8]) {
#pragma unroll
    for (int kk = 0; kk < 4; ++kk) {
        short8 b[8];
#pragma unroll
        for (int nt = 0; nt < 8; ++nt)
            b[nt] = *(const short8*)&Wl[(nt * 16 + c) * LDW + kk * 32 + q * 8];
        short8 a = ldA8(A + c * LDA + kk * 32 + q * 8);
#pragma unroll
        for (int nt = 0; nt < 8; ++nt)
            acc[nt] = __builtin_amdgcn_mfma_f32_16x16x32_bf16(a, b[nt], acc[nt], 0, 0, 0);
    }
}

__device__ __forceinline__ void zero8(f32x4 a[8]) {
#pragma unroll
    for (int nt = 0; nt < 8; ++nt) a[nt] = (f32x4){0.f, 0.f, 0.f, 0.f};
}

// per-token LN stats (R5-proven): token = lane&15, partials across 4 quads
__device__ __forceinline__ void ln_stats(const float* t, float& mu, float& rs) {
    float s1 = 0.f, s2 = 0.f;
#pragma unroll
    for (int i = 0; i < 32; ++i) { s1 += t[i]; s2 += t[i] * t[i]; }
    s1 += __shfl_xor(s1, 16); s2 += __shfl_xor(s2, 16);
    s1 += __shfl_xor(s1, 32); s2 += __shfl_xor(s2, 32);
    mu = s1 * (1.f / 128.f);
    rs = rsqrtf(s2 * (1.f / 128.f) - mu * mu + 1e-5f);
}

template<bool PRE>
__global__ __launch_bounds__(256) void rwkv_mfma(
    const float* __restrict__ X,
    const float* __restrict__ G0, const float* __restrict__ B0,
    const float* __restrict__ G1, const float* __restrict__ B1,
    const float* __restrict__ G2, const float* __restrict__ B2,
    const float* __restrict__ WoutF, const float* __restrict__ WwhtF,
    const float* __restrict__ WkeyF, const float* __restrict__ WrecF,
    const float* __restrict__ WvalF,
    const ushort* __restrict__ Wb,
    float* __restrict__ Y)
{
    __shared__ __align__(16) ushort actS[NW * TPW * LDA];  // wave-local slices
    __shared__ __align__(16) ushort whtS[NW * TPW * LDA];
    __shared__ __align__(16) ushort Wlds[128 * LDW];       // staged weight tile

    const int tid = threadIdx.x;
    const int w = tid >> 6, l = tid & 63;
    const int q = l >> 4, c = l & 15;
    ushort* act = actS + w * (TPW * LDA);   // a1 / y2 / k-chunk / prod (bf16)
    ushort* wht = whtS + w * (TPW * LDA);   // att temp, then wht (bf16)

    const int s64 = blockIdx.x * 64;           // 64 tokens per block
    const int bb  = s64 >> 14;
    const int s0  = s64 & (HW - 1);
    const long gbase = (long)(bb * CDIM) * HW + s0 + 16 * w + c;

    // ---- stage W_out early (overlaps with X loads + LN); no readers yet ----
    stageW<PRE>(Wlds, Wb + OFF_OUT, WoutF, 128, 0, 0, tid);

    // ---- residual: token 16w+c, channels 32q..32q+31 (R5 geometry) ----
    float t[32];
#pragma unroll
    for (int i = 0; i < 32; ++i) t[i] = X[gbase + (long)(32 * q + i) * HW];

    float mu, rs;
    // ---- LN0 ----
    ln_stats(t, mu, rs);
#pragma unroll
    for (int i = 0; i < 32; ++i) {
        int ch = 32 * q + i;
        t[i] = (t[i] - mu) * rs * G0[ch] + B0[ch];
    }
    // ---- LN1 + silu -> act (bf16, wave-local) ----
    ln_stats(t, mu, rs);
#pragma unroll
    for (int j = 0; j < 16; ++j) {
        int ch = 32 * q + 2 * j;
        float y0 = (t[2*j]   - mu) * rs * G1[ch]   + B1[ch];
        float y1 = (t[2*j+1] - mu) * rs * G1[ch+1] + B1[ch+1];
        y0 *= sigm(y0); y1 *= sigm(y1);
        *(uint*)&act[c * LDA + ch] = (uint)f2bf(y0) | ((uint)f2bf(y1) << 16);
    }
    __syncthreads();                           // W_out tile + a1 visible

    // ---- att = a1 @ W_out^T -> wht buffer (att temp, bf16) ----
    f32x4 acc[8];
    zero8(acc);
    gemm16(act, Wlds, q, c, acc);
#pragma unroll
    for (int nt = 0; nt < 8; ++nt)
#pragma unroll
        for (int r = 0; r < 4; ++r)
            wht[(q * 4 + r) * LDA + nt * 16 + c] = f2bf(acc[nt][r]);
    __syncthreads();                           // att visible; Wlds+act readers done
#pragma unroll
    for (int i = 0; i < 32; ++i)
        t[i] += bf2f(wht[c * LDA + 32 * q + i]);    // t1 = t + att

    // ---- LN2; stage W_whiten (readers done at last barrier) ----
    ln_stats(t, mu, rs);
    stageW<PRE>(Wlds, Wb + OFF_WHT, WwhtF, 128, 0, 0, tid);
#pragma unroll
    for (int j = 0; j < 16; ++j) {
        int ch = 32 * q + 2 * j;
        float y0 = (t[2*j]   - mu) * rs * G2[ch]   + B2[ch];
        float y1 = (t[2*j+1] - mu) * rs * G2[ch+1] + B2[ch+1];
        *(uint*)&act[c * LDA + ch] = (uint)f2bf(y0) | ((uint)f2bf(y1) << 16);
    }
    __syncthreads();                           // W_whiten + y2 visible

    // ---- wht = y2 @ W_whiten^T -> wht buffer (overwrites att temp; att last
    //      read pre-barrier) ----
    zero8(acc);
    gemm16(act, Wlds, q, c, acc);
#pragma unroll
    for (int nt = 0; nt < 8; ++nt)
#pragma unroll
        for (int r = 0; r < 4; ++r)
            wht[(q * 4 + r) * LDA + nt * 16 + c] = f2bf(acc[nt][r]);
    __syncthreads();                           // wht visible; Wlds readers done

    // ---- kv = sum_chunks relu(wht @ W_key^T)^2 @ W_value^T ----
    f32x4 akv[8];
    zero8(akv);
    for (int chunk = 0; chunk < 4; ++chunk) {
        stageW<PRE>(Wlds, Wb + OFF_KEY, WkeyF, 128, chunk * 128, 0, tid);
        __syncthreads();                       // key tile ready
        zero8(acc);
        gemm16(wht, Wlds, q, c, acc);
        __syncthreads();                       // key-tile + act readers done
        stageW<PRE>(Wlds, Wb + OFF_VAL, WvalF, 512, 0, chunk * 128, tid);
#pragma unroll
        for (int nt = 0; nt < 8; ++nt)
#pragma unroll
            for (int r = 0; r < 4; ++r) {
                float v = fmaxf(acc[nt][r], 0.f);
                act[(q * 4 + r) * LDA + nt * 16 + c] = f2bf(v * v);
            }
        __syncthreads();                       // val tile + k-chunk visible
        gemm16(act, Wlds, q, c, akv);
        __syncthreads();                       // val-tile + act readers done
    }

    // ---- r = sigmoid(wht @ W_recep^T); prod = r*kv -> act (bf16) ----
    stageW<PRE>(Wlds, Wb + OFF_REC, WrecF, 128, 0, 0, tid);
    __syncthreads();                           // rec tile ready
    zero8(acc);
    gemm16(wht, Wlds, q, c, acc);
#pragma unroll
    for (int nt = 0; nt < 8; ++nt)
#pragma unroll
        for (int r = 0; r < 4; ++r)
            act[(q * 4 + r) * LDA + nt * 16 + c] =
                f2bf(sigm(acc[nt][r]) * akv[nt][r]);
    __syncthreads();                           // prod visible

    // ---- out = 2 * (t1 + r*kv) ----
#pragma unroll
    for (int i = 0; i < 32; ++i) {
        float t2 = t[i] + bf2f(act[c * LDA + 32 * q + i]);
        Y[gbase + (long)(32 * q + i) * HW] = 2.f * t2;
    }
}

extern "C" void kernel_launch(void* const* d_in, const int* in_sizes, int n_in,
                              void* d_out, int out_size, void* d_ws, size_t ws_size,
                              hipStream_t stream) {
    (void)in_sizes; (void)n_in; (void)out_size;
    const float* X  = (const float*)d_in[0];
    const float* G0 = (const float*)d_in[1];  const float* B0 = (const float*)d_in[2];
    const float* G1 = (const float*)d_in[3];  const float* B1 = (const float*)d_in[4];
    const float* G2 = (const float*)d_in[5];  const float* B2 = (const float*)d_in[6];
    const float* Wout = (const float*)d_in[7];
    const float* Wwht = (const float*)d_in[8];
    const float* Wkey = (const float*)d_in[9];
    const float* Wrec = (const float*)d_in[10];
    const float* Wval = (const float*)d_in[11];
    float* Y = (float*)d_out;

    const bool pre = ws_size >= (size_t)WS_ELEMS * 2;
    if (pre) {
        ushort* ws = (ushort*)d_ws;
        cvt_all<<<704, 256, 0, stream>>>(Wout, Wwht, Wkey, Wrec, Wval, ws);
        rwkv_mfma<true><<<1024, 256, 0, stream>>>(
            X, G0, B0, G1, B1, G2, B2,
            Wout, Wwht, Wkey, Wrec, Wval, ws, Y);
    } else {
        rwkv_mfma<false><<<1024, 256, 0, stream>>>(
            X, G0, B0, G1, B1, G2, B2,
            Wout, Wwht, Wkey, Wrec, Wval, nullptr, Y);
    }
}